// Round 1
// baseline (5595.309 us; speedup 1.0000x reference)
//
#include <hip/hip_runtime.h>

// MLA: B=2, N=NKV=2048, E=4096, H=16, HD=256, LQ=512, LKV=256
// out = softmax( (Q Wq_d W_qk) . (K Wkv_d)^T / 16 ) . (K Wkv_d Wv_u)
//
// Round 0: all-fp32 baseline.
//   sgemm128: generic fp32 GEMM, 128x128 tile, BK=16, 8x8 per thread.
//   flash_fp32: online-softmax attention, TQ=16 q rows per block, TK=16 key tiles.

#define B_ 2
#define N_ 2048
#define H_ 16
#define HD_ 256
#define LKV_ 256

// ---------------- SGEMM: C[M,N] = A[M,K] * B[K,N], fp32 row-major ----------------
__global__ __launch_bounds__(256) void sgemm128(
    const float* __restrict__ A, const float* __restrict__ Bm, float* __restrict__ C,
    int M, int N, int K)
{
  __shared__ float As[16][132];   // [k][m], pad 132: 528B row stride, 16B aligned, bank stride 4
  __shared__ float Bs[16][132];   // [k][n], same pad

  const int t  = threadIdx.x;
  const int tx = t & 15, ty = t >> 4;
  const int m0 = blockIdx.y * 128, n0 = blockIdx.x * 128;

  float acc[8][8];
#pragma unroll
  for (int i = 0; i < 8; ++i)
#pragma unroll
    for (int j = 0; j < 8; ++j) acc[i][j] = 0.f;

  const int ar0 = t >> 2, ak0 = (t & 3) * 4;   // A: 128 rows x 4 float4
  const int br0 = t >> 5, bc0 = (t & 31) * 4;  // B: 16 rows x 32 float4

  const float* Ap = A + (size_t)m0 * K;
  const float* Bp = Bm + n0;

  for (int k0 = 0; k0 < K; k0 += 16) {
    float4 a0 = *(const float4*)(Ap + (size_t)(ar0)      * K + k0 + ak0);
    float4 a1 = *(const float4*)(Ap + (size_t)(ar0 + 64) * K + k0 + ak0);
    float4 b0 = *(const float4*)(Bp + (size_t)(k0 + br0)     * N + bc0);
    float4 b1 = *(const float4*)(Bp + (size_t)(k0 + br0 + 8) * N + bc0);
    __syncthreads();
    As[ak0+0][ar0] = a0.x; As[ak0+1][ar0] = a0.y; As[ak0+2][ar0] = a0.z; As[ak0+3][ar0] = a0.w;
    As[ak0+0][ar0+64] = a1.x; As[ak0+1][ar0+64] = a1.y; As[ak0+2][ar0+64] = a1.z; As[ak0+3][ar0+64] = a1.w;
    *(float4*)(&Bs[br0][bc0])   = b0;
    *(float4*)(&Bs[br0+8][bc0]) = b1;
    __syncthreads();
#pragma unroll
    for (int kk = 0; kk < 16; ++kk) {
      float4 av0 = *(const float4*)(&As[kk][ty * 4]);
      float4 av1 = *(const float4*)(&As[kk][64 + ty * 4]);
      float4 bv0 = *(const float4*)(&Bs[kk][tx * 4]);
      float4 bv1 = *(const float4*)(&Bs[kk][64 + tx * 4]);
      float ar[8] = {av0.x, av0.y, av0.z, av0.w, av1.x, av1.y, av1.z, av1.w};
      float br[8] = {bv0.x, bv0.y, bv0.z, bv0.w, bv1.x, bv1.y, bv1.z, bv1.w};
#pragma unroll
      for (int i = 0; i < 8; ++i)
#pragma unroll
        for (int j = 0; j < 8; ++j) acc[i][j] += ar[i] * br[j];
    }
  }

#pragma unroll
  for (int i = 0; i < 8; ++i) {
    int row = m0 + (i >> 2) * 64 + ty * 4 + (i & 3);
    float* cp = C + (size_t)row * N + n0;
    float4 v0 = {acc[i][0], acc[i][1], acc[i][2], acc[i][3]};
    float4 v1 = {acc[i][4], acc[i][5], acc[i][6], acc[i][7]};
    *(float4*)(cp + tx * 4)      = v0;
    *(float4*)(cp + 64 + tx * 4) = v1;
  }
}

// ---------------- Flash attention, fp32, online softmax ----------------
// Block: 256 threads, one (b, h, 16-query tile). Key tiles of 16.
// Thread (q = t>>4, lane16 = t&15): S-phase computes S[q][lane16] full dot;
// P.V phase accumulates O[q][d], d = 64c + 4*lane16 + j.
__global__ __launch_bounds__(256) void flash_fp32(
    const float* __restrict__ q2,   // [B,N,H,LKV]
    const float* __restrict__ ckv,  // [B,NKV,LKV]
    const float* __restrict__ vup,  // [B,NKV,H,HD]
    float* __restrict__ out)        // [B,N,H*HD]
{
  __shared__ float Qt[16][260];
  __shared__ float Kt[16][260];
  __shared__ float Vt[16][260];
  __shared__ float Sm[16][17];

  const int t  = threadIdx.x;
  const int blk = blockIdx.x;
  const int qt = blk & 127;          // N/16 = 128 q-tiles
  const int h  = (blk >> 7) & 15;
  const int b  = blk >> 11;
  const int n0 = qt * 16;

  const int q  = t >> 4;   // 0..15 query row within tile
  const int dg = t & 15;   // lane-in-group: key index in S-phase, d-group in PV

  // stage Q tile (16 x 256), row stride in global = H*LKV = 4096
  {
    const float* src = q2 + ((size_t)(b * N_ + n0) * H_ + h) * LKV_;
#pragma unroll
    for (int i = 0; i < 4; ++i) {
      int f = t + 256 * i;            // 1024 float4
      int row = f >> 6, c4 = f & 63;
      float4 v = *(const float4*)(src + (size_t)row * (H_ * LKV_) + c4 * 4);
      *(float4*)(&Qt[row][c4 * 4]) = v;
    }
  }

  float m = -1e30f, l = 0.f;
  float o[4][4];
#pragma unroll
  for (int c = 0; c < 4; ++c)
#pragma unroll
    for (int j = 0; j < 4; ++j) o[c][j] = 0.f;

  const float* kbase = ckv + (size_t)(b * N_) * LKV_;
  const float* vbase = vup + ((size_t)(b * N_) * H_ + h) * HD_;

  for (int k0 = 0; k0 < N_; k0 += 16) {
    __syncthreads();
    // stage K tile and V tile (16 x 256 each)
#pragma unroll
    for (int i = 0; i < 4; ++i) {
      int f = t + 256 * i;
      int row = f >> 6, c4 = f & 63;
      float4 kv = *(const float4*)(kbase + (size_t)(k0 + row) * LKV_ + c4 * 4);
      *(float4*)(&Kt[row][c4 * 4]) = kv;
      float4 vv = *(const float4*)(vbase + (size_t)(k0 + row) * (H_ * HD_) + c4 * 4);
      *(float4*)(&Vt[row][c4 * 4]) = vv;
    }
    __syncthreads();

    // S[q][dg] = (Q[q] . K[dg]) / 16
    float s = 0.f;
#pragma unroll 16
    for (int l4 = 0; l4 < 64; ++l4) {
      float4 qv = *(const float4*)(&Qt[q][l4 * 4]);
      float4 kv = *(const float4*)(&Kt[dg][l4 * 4]);
      s += qv.x * kv.x + qv.y * kv.y + qv.z * kv.z + qv.w * kv.w;
    }
    s *= 0.0625f;

    // online softmax over the 16 lanes sharing q
    float mx = s;
#pragma unroll
    for (int off = 1; off < 16; off <<= 1)
      mx = fmaxf(mx, __shfl_xor(mx, off, 16));
    float m_new = fmaxf(m, mx);
    float p = __expf(s - m_new);
    float sum = p;
#pragma unroll
    for (int off = 1; off < 16; off <<= 1)
      sum += __shfl_xor(sum, off, 16);
    float alpha = __expf(m - m_new);
    l = l * alpha + sum;
    m = m_new;
    Sm[q][dg] = p;
#pragma unroll
    for (int c = 0; c < 4; ++c)
#pragma unroll
      for (int j = 0; j < 4; ++j) o[c][j] *= alpha;
    __syncthreads();

    // O[q][64c + 4dg + j] += sum_k P[q][k] * V[k][...]
#pragma unroll
    for (int k = 0; k < 16; ++k) {
      float pk = Sm[q][k];
#pragma unroll
      for (int c = 0; c < 4; ++c) {
        float4 vv = *(const float4*)(&Vt[k][c * 64 + dg * 4]);
        o[c][0] += pk * vv.x; o[c][1] += pk * vv.y;
        o[c][2] += pk * vv.z; o[c][3] += pk * vv.w;
      }
    }
  }

  float inv = 1.f / l;
  float* dst = out + ((size_t)(b * N_ + n0 + q) * H_ + h) * HD_;
#pragma unroll
  for (int c = 0; c < 4; ++c) {
    float4 vv = {o[c][0] * inv, o[c][1] * inv, o[c][2] * inv, o[c][3] * inv};
    *(float4*)(dst + c * 64 + dg * 4) = vv;
  }
}

extern "C" void kernel_launch(void* const* d_in, const int* in_sizes, int n_in,
                              void* d_out, int out_size, void* d_ws, size_t ws_size,
                              hipStream_t stream) {
  const float* Q     = (const float*)d_in[0];  // [2,2048,4096]
  const float* Kin   = (const float*)d_in[1];  // [2,2048,4096]
  const float* Wq_d  = (const float*)d_in[2];  // [4096,512]
  const float* W_qk  = (const float*)d_in[3];  // [512,4096]
  const float* Wkv_d = (const float*)d_in[4];  // [4096,256]
  const float* Wv_u  = (const float*)d_in[5];  // [256,4096]
  float* out = (float*)d_out;

  float* ws  = (float*)d_ws;
  float* cq  = ws;                  // [4096, 512]   = 2,097,152
  float* ckv = cq  + 2097152;       // [4096, 256]   = 1,048,576
  float* q2  = ckv + 1048576;       // [4096, 4096]  = 16,777,216
  float* vup = q2  + 16777216;      // [4096, 4096]  = 16,777,216
  // total ws: 36,700,160 floats = 140 MB

  // C_q = Q @ Wq_d          [4096 x 512],  K=4096
  sgemm128<<<dim3(512 / 128, 4096 / 128), 256, 0, stream>>>(Q, Wq_d, cq, 4096, 512, 4096);
  // C_kv = K @ Wkv_d        [4096 x 256],  K=4096
  sgemm128<<<dim3(256 / 128, 4096 / 128), 256, 0, stream>>>(Kin, Wkv_d, ckv, 4096, 256, 4096);
  // Q2 = C_q @ W_qk         [4096 x 4096], K=512
  sgemm128<<<dim3(4096 / 128, 4096 / 128), 256, 0, stream>>>(cq, W_qk, q2, 4096, 4096, 512);
  // V_up = C_kv @ Wv_u      [4096 x 4096], K=256
  sgemm128<<<dim3(4096 / 128, 4096 / 128), 256, 0, stream>>>(ckv, Wv_u, vup, 4096, 4096, 256);
  // attention
  flash_fp32<<<dim3(B_ * H_ * (N_ / 16)), 256, 0, stream>>>(q2, ckv, vup, out);
}

// Round 3
// 1920.913 us; speedup vs baseline: 2.9128x; 2.9128x over previous
//
#include <hip/hip_runtime.h>

// MLA: B=2, N=NKV=2048, E=4096, H=16, HD=256, LQ=512, LKV=256
// Round 2: fix compile error in transpose_v (stray artifact line removed).
//   flash attention on bf16 MFMA (16x16x32), fp32 GEMMs kept.

#define B_ 2
#define N_ 2048
#define H_ 16
#define HD_ 256
#define LKV_ 256

typedef __attribute__((ext_vector_type(8))) short bf8;           // 8 x bf16 (4 VGPR)
typedef __attribute__((ext_vector_type(4))) float f4;            // MFMA C/D frag
typedef __attribute__((ext_vector_type(4))) unsigned short us4v;
typedef unsigned short u16;

__device__ __forceinline__ u16 f2b(float f) {
  union { float f; unsigned u; } v; v.f = f;
  unsigned r = (v.u + 0x7FFFu + ((v.u >> 16) & 1u)) >> 16;
  return (u16)r;
}

// ---------------- SGEMM: C[M,N] = A[M,K] * B[K,N], fp32 in, fp32 or bf16 out ----------------
__global__ __launch_bounds__(256) void sgemm128(
    const float* __restrict__ A, const float* __restrict__ Bm, void* __restrict__ C,
    int M, int N, int K, int obf16)
{
  __shared__ float As[16][132];
  __shared__ float Bs[16][132];

  const int t  = threadIdx.x;
  const int tx = t & 15, ty = t >> 4;
  const int m0 = blockIdx.y * 128, n0 = blockIdx.x * 128;

  float acc[8][8];
#pragma unroll
  for (int i = 0; i < 8; ++i)
#pragma unroll
    for (int j = 0; j < 8; ++j) acc[i][j] = 0.f;

  const int ar0 = t >> 2, ak0 = (t & 3) * 4;
  const int br0 = t >> 5, bc0 = (t & 31) * 4;

  const float* Ap = A + (size_t)m0 * K;
  const float* Bp = Bm + n0;

  for (int k0 = 0; k0 < K; k0 += 16) {
    float4 a0 = *(const float4*)(Ap + (size_t)(ar0)      * K + k0 + ak0);
    float4 a1 = *(const float4*)(Ap + (size_t)(ar0 + 64) * K + k0 + ak0);
    float4 b0 = *(const float4*)(Bp + (size_t)(k0 + br0)     * N + bc0);
    float4 b1 = *(const float4*)(Bp + (size_t)(k0 + br0 + 8) * N + bc0);
    __syncthreads();
    As[ak0+0][ar0] = a0.x; As[ak0+1][ar0] = a0.y; As[ak0+2][ar0] = a0.z; As[ak0+3][ar0] = a0.w;
    As[ak0+0][ar0+64] = a1.x; As[ak0+1][ar0+64] = a1.y; As[ak0+2][ar0+64] = a1.z; As[ak0+3][ar0+64] = a1.w;
    *(float4*)(&Bs[br0][bc0])   = b0;
    *(float4*)(&Bs[br0+8][bc0]) = b1;
    __syncthreads();
#pragma unroll
    for (int kk = 0; kk < 16; ++kk) {
      float4 av0 = *(const float4*)(&As[kk][ty * 4]);
      float4 av1 = *(const float4*)(&As[kk][64 + ty * 4]);
      float4 bv0 = *(const float4*)(&Bs[kk][tx * 4]);
      float4 bv1 = *(const float4*)(&Bs[kk][64 + tx * 4]);
      float ar[8] = {av0.x, av0.y, av0.z, av0.w, av1.x, av1.y, av1.z, av1.w};
      float br[8] = {bv0.x, bv0.y, bv0.z, bv0.w, bv1.x, bv1.y, bv1.z, bv1.w};
#pragma unroll
      for (int i = 0; i < 8; ++i)
#pragma unroll
        for (int j = 0; j < 8; ++j) acc[i][j] += ar[i] * br[j];
    }
  }

#pragma unroll
  for (int i = 0; i < 8; ++i) {
    int row = m0 + (i >> 2) * 64 + ty * 4 + (i & 3);
    if (!obf16) {
      float* cp = (float*)C + (size_t)row * N + n0;
      float4 v0 = {acc[i][0], acc[i][1], acc[i][2], acc[i][3]};
      float4 v1 = {acc[i][4], acc[i][5], acc[i][6], acc[i][7]};
      *(float4*)(cp + tx * 4)      = v0;
      *(float4*)(cp + 64 + tx * 4) = v1;
    } else {
      u16* cp = (u16*)C + (size_t)row * N + n0;
      us4v v0 = {f2b(acc[i][0]), f2b(acc[i][1]), f2b(acc[i][2]), f2b(acc[i][3])};
      us4v v1 = {f2b(acc[i][4]), f2b(acc[i][5]), f2b(acc[i][6]), f2b(acc[i][7])};
      *(us4v*)(cp + tx * 4)      = v0;
      *(us4v*)(cp + 64 + tx * 4) = v1;
    }
  }
}

// ---------------- fp32 -> bf16 elementwise (for ckv) ----------------
__global__ __launch_bounds__(256) void cvt_bf16(const float* __restrict__ src,
                                                u16* __restrict__ dst, int n4)
{
  int i = blockIdx.x * 256 + threadIdx.x;
  if (i < n4) {
    float4 v = *(const float4*)(src + (size_t)i * 4);
    us4v o = {f2b(v.x), f2b(v.y), f2b(v.z), f2b(v.w)};
    *(us4v*)(dst + (size_t)i * 4) = o;
  }
}

// ---------------- transpose vupB [B,NKV,H,HD](bf16) -> vupT [B,H,HD,NKV](bf16) ----------------
__global__ __launch_bounds__(256) void transpose_v(const u16* __restrict__ vupB,
                                                   u16* __restrict__ vupT)
{
  __shared__ u16 tile[64][78];
  const int t = threadIdx.x;
  const int key0 = blockIdx.x * 64, d0 = blockIdx.y * 64;
  const int bh = blockIdx.z, b = bh >> 4, h = bh & 15;

  // read: 64 keys x 64 d, 8-bf16 chunks
#pragma unroll
  for (int i = 0; i < 2; ++i) {
    int c = t + 256 * i;           // 512 chunks
    int key = c >> 3, d8 = c & 7;
    bf8 v = *(const bf8*)(vupB + ((size_t)(b * N_ + key0 + key) * (H_ * HD_)) + h * HD_ + d0 + d8 * 8);
    *(bf8*)(&tile[key][d8 * 8]) = v;
  }
  __syncthreads();
  // write: 64 d x 64 keys
#pragma unroll
  for (int i = 0; i < 2; ++i) {
    int c = t + 256 * i;
    int d = c >> 3, k8 = c & 7;
    bf8 v;
#pragma unroll
    for (int j = 0; j < 8; ++j) v[j] = (short)tile[k8 * 8 + j][d];
    *(bf8*)(vupT + ((size_t)bh * HD_ + d0 + d) * (size_t)N_ + key0 + k8 * 8) = v;
  }
}

// ---------------- flash attention: bf16 MFMA, online softmax ----------------
// Block: 256 threads (4 waves), 128 q rows (32/wave), key tiles of 32.
__global__ __launch_bounds__(256, 2) void flash_mfma(
    const u16* __restrict__ q2b,   // [B,N,H,LKV] bf16
    const u16* __restrict__ ckvb,  // [B,NKV,LKV] bf16
    const u16* __restrict__ vupT,  // [B,H,HD,NKV] bf16
    float* __restrict__ out)       // [B,N,H*HD] fp32
{
  __shared__ u16 KtL[32 * 264];    // [key][lat], pad 264
  __shared__ u16 VtL[256 * 40];    // [d][key], pad 40
  __shared__ u16 PtL[128 * 40];    // [q][key], pad 40

  const int t = threadIdx.x;
  const int w = t >> 6, lane = t & 63;
  const int quad = lane >> 4, l16 = lane & 15;
  const int n0 = blockIdx.x * 128;
  const int bh = blockIdx.y, b = bh >> 4, h = bh & 15;

  // Q fragments in registers: 2 M-tiles x 8 k-steps (A-layout: m=l16, k=quad*8+j)
  bf8 qf[2][8];
  {
    const u16* qbase = q2b + (size_t)(b * N_ + n0 + w * 32 + l16) * (H_ * LKV_) + h * LKV_ + quad * 8;
#pragma unroll
    for (int mi = 0; mi < 2; ++mi)
#pragma unroll
      for (int ks = 0; ks < 8; ++ks)
        qf[mi][ks] = *(const bf8*)(qbase + (size_t)(mi * 16) * (H_ * LKV_) + ks * 32);
  }

  f4 o[2][16];
#pragma unroll
  for (int mi = 0; mi < 2; ++mi)
#pragma unroll
    for (int dt = 0; dt < 16; ++dt) o[mi][dt] = (f4){0.f, 0.f, 0.f, 0.f};
  float ms[2][4], ls[2][4];
#pragma unroll
  for (int mi = 0; mi < 2; ++mi)
#pragma unroll
    for (int r = 0; r < 4; ++r) { ms[mi][r] = -1e30f; ls[mi][r] = 0.f; }

  const u16* kgb = ckvb + (size_t)b * N_ * LKV_;
  const u16* vgb = vupT + (size_t)bh * HD_ * N_;

  for (int k0 = 0; k0 < N_; k0 += 32) {
    __syncthreads();
    // stage K tile: 32 keys x 256 lat
#pragma unroll
    for (int i = 0; i < 4; ++i) {
      int c = t + 256 * i;              // 1024 chunks of 8
      int key = c >> 5, l8 = c & 31;
      bf8 v = *(const bf8*)(kgb + (size_t)(k0 + key) * LKV_ + l8 * 8);
      *(bf8*)(&KtL[key * 264 + l8 * 8]) = v;
    }
    // stage V tile (transposed): 256 d x 32 keys
#pragma unroll
    for (int i = 0; i < 4; ++i) {
      int c = t + 256 * i;
      int d = c >> 2, k8 = c & 3;
      bf8 v = *(const bf8*)(vgb + (size_t)d * N_ + k0 + k8 * 8);
      *(bf8*)(&VtL[d * 40 + k8 * 8]) = v;
    }
    __syncthreads();

    // S = Q K^T  (2 M-tiles x 2 N-tiles, K=256 over 8 MFMA steps)
    f4 sf[2][2];
    sf[0][0] = (f4){0,0,0,0}; sf[0][1] = (f4){0,0,0,0};
    sf[1][0] = (f4){0,0,0,0}; sf[1][1] = (f4){0,0,0,0};
#pragma unroll
    for (int nt = 0; nt < 2; ++nt) {
      const u16* kr = &KtL[(nt * 16 + l16) * 264 + quad * 8];
#pragma unroll
      for (int ks = 0; ks < 8; ++ks) {
        bf8 kf = *(const bf8*)(kr + ks * 32);
        sf[0][nt] = __builtin_amdgcn_mfma_f32_16x16x32_bf16(qf[0][ks], kf, sf[0][nt], 0, 0, 0);
        sf[1][nt] = __builtin_amdgcn_mfma_f32_16x16x32_bf16(qf[1][ks], kf, sf[1][nt], 0, 0, 0);
      }
    }

    // online softmax per row (row = quad*4 + r within M-tile)
#pragma unroll
    for (int mi = 0; mi < 2; ++mi) {
      float al[4];
#pragma unroll
      for (int r = 0; r < 4; ++r) {
        float a0 = sf[mi][0][r] * 0.0625f;
        float a1 = sf[mi][1][r] * 0.0625f;
        float mx = fmaxf(a0, a1);
#pragma unroll
        for (int off = 1; off < 16; off <<= 1) mx = fmaxf(mx, __shfl_xor(mx, off, 16));
        float mn = fmaxf(ms[mi][r], mx);
        float p0 = __expf(a0 - mn), p1 = __expf(a1 - mn);
        float sum = p0 + p1;
#pragma unroll
        for (int off = 1; off < 16; off <<= 1) sum += __shfl_xor(sum, off, 16);
        al[r] = __expf(ms[mi][r] - mn);
        ls[mi][r] = ls[mi][r] * al[r] + sum;
        ms[mi][r] = mn;
        int q = w * 32 + mi * 16 + quad * 4 + r;
        PtL[q * 40 + l16]      = f2b(p0);
        PtL[q * 40 + 16 + l16] = f2b(p1);
      }
#pragma unroll
      for (int dt = 0; dt < 16; ++dt) {
        o[mi][dt][0] *= al[0]; o[mi][dt][1] *= al[1];
        o[mi][dt][2] *= al[2]; o[mi][dt][3] *= al[3];
      }
    }
    __syncthreads();

    // O += P V  (K=32 keys in one MFMA step; A-layout P from LDS)
    bf8 pf0 = *(const bf8*)(&PtL[(w * 32 + l16) * 40 + quad * 8]);
    bf8 pf1 = *(const bf8*)(&PtL[(w * 32 + 16 + l16) * 40 + quad * 8]);
#pragma unroll
    for (int dt = 0; dt < 16; ++dt) {
      bf8 vf = *(const bf8*)(&VtL[(dt * 16 + l16) * 40 + quad * 8]);
      o[0][dt] = __builtin_amdgcn_mfma_f32_16x16x32_bf16(pf0, vf, o[0][dt], 0, 0, 0);
      o[1][dt] = __builtin_amdgcn_mfma_f32_16x16x32_bf16(pf1, vf, o[1][dt], 0, 0, 0);
    }
  }

  // epilogue: out[b][n][h*256 + d] = o / l
#pragma unroll
  for (int mi = 0; mi < 2; ++mi)
#pragma unroll
    for (int r = 0; r < 4; ++r) {
      float iv = 1.f / ls[mi][r];
      float* dst = out + (size_t)(b * N_ + n0 + w * 32 + mi * 16 + quad * 4 + r) * (H_ * HD_)
                   + h * HD_ + l16;
#pragma unroll
      for (int dt = 0; dt < 16; ++dt) dst[dt * 16] = o[mi][dt][r] * iv;
    }
}

extern "C" void kernel_launch(void* const* d_in, const int* in_sizes, int n_in,
                              void* d_out, int out_size, void* d_ws, size_t ws_size,
                              hipStream_t stream) {
  const float* Q     = (const float*)d_in[0];
  const float* Kin   = (const float*)d_in[1];
  const float* Wq_d  = (const float*)d_in[2];
  const float* W_qk  = (const float*)d_in[3];
  const float* Wkv_d = (const float*)d_in[4];
  const float* Wv_u  = (const float*)d_in[5];
  float* out = (float*)d_out;

  char* ws = (char*)d_ws;
  float* cq   = (float*)(ws);                       //  8 MB fp32 [4096,512]
  float* ckv  = (float*)(ws + 8388608);             //  4 MB fp32 [4096,256]
  u16*   q2b  = (u16*)  (ws + 12582912);            // 32 MB bf16 [4096,4096]
  u16*   vupB = (u16*)  (ws + 46137344);            // 32 MB bf16 [4096,4096]
  u16*   ckvb = (u16*)  (ws + 79691776);            //  2 MB bf16 [4096,256]
  u16*   vupT = (u16*)  (ws + 81788928);            // 32 MB bf16 [B,H,256,2048]

  // C_q = Q @ Wq_d (fp32)
  sgemm128<<<dim3(4, 32), 256, 0, stream>>>(Q, Wq_d, cq, 4096, 512, 4096, 0);
  // C_kv = K @ Wkv_d (fp32)
  sgemm128<<<dim3(2, 32), 256, 0, stream>>>(Kin, Wkv_d, ckv, 4096, 256, 4096, 0);
  // Q2 = C_q @ W_qk (bf16 out)
  sgemm128<<<dim3(32, 32), 256, 0, stream>>>(cq, W_qk, q2b, 4096, 4096, 512, 1);
  // V_up = C_kv @ Wv_u (bf16 out)
  sgemm128<<<dim3(32, 32), 256, 0, stream>>>(ckv, Wv_u, vupB, 4096, 4096, 256, 1);
  // ckv -> bf16
  cvt_bf16<<<dim3(1024), 256, 0, stream>>>(ckv, ckvb, 262144);
  // vupB -> vupT (transpose)
  transpose_v<<<dim3(32, 4, 32), 256, 0, stream>>>(vupB, vupT);
  // flash attention
  flash_mfma<<<dim3(16, 32), 256, 0, stream>>>(q2b, ckvb, vupT, out);
}

// Round 4
// 790.381 us; speedup vs baseline: 7.0793x; 2.4304x over previous
//
#include <hip/hip_runtime.h>

// MLA: B=2, N=NKV=2048, E=4096, H=16, HD=256, LQ=512, LKV=256
// Round 3: all four GEMMs moved to bf16 MFMA (m97-style: 128x128 tile, BK=32,
//   global_load_lds width=16). Weights pre-transposed to [N,K] bf16.
//   Flash attention kernel unchanged from R2 (verified).

#define B_ 2
#define N_ 2048
#define H_ 16
#define HD_ 256
#define LKV_ 256

typedef __attribute__((ext_vector_type(8))) short bf8;           // 8 x bf16 (4 VGPR)
typedef __attribute__((ext_vector_type(4))) float f4;            // MFMA C/D frag
typedef __attribute__((ext_vector_type(4))) unsigned short us4v;
typedef unsigned short u16;

__device__ __forceinline__ u16 f2b(float f) {
  union { float f; unsigned u; } v; v.f = f;
  unsigned r = (v.u + 0x7FFFu + ((v.u >> 16) & 1u)) >> 16;
  return (u16)r;
}

// global -> LDS direct copy, 16B per lane (CK-style addrspace plumbing)
__device__ __forceinline__ void load_lds16(const void* g, void* l) {
  __builtin_amdgcn_global_load_lds(
      (const __attribute__((address_space(1))) unsigned int*)(unsigned long long)(uintptr_t)g,
      (__attribute__((address_space(3))) unsigned int*)(unsigned int)(uintptr_t)l,
      16, 0, 0);
}

// ---------------- fp32 -> bf16 elementwise ----------------
__global__ __launch_bounds__(256) void cvt_bf16(const float* __restrict__ src,
                                                u16* __restrict__ dst, int n4)
{
  int i = blockIdx.x * 256 + threadIdx.x;
  if (i < n4) {
    float4 v = *(const float4*)(src + (size_t)i * 4);
    us4v o = {f2b(v.x), f2b(v.y), f2b(v.z), f2b(v.w)};
    *(us4v*)(dst + (size_t)i * 4) = o;
  }
}

// ---------------- fp32 [R,C] -> bf16 [C,R] (weight transpose) ----------------
__global__ __launch_bounds__(256) void cvt_transpose(const float* __restrict__ src,
                                                     u16* __restrict__ dst, int R, int C)
{
  __shared__ float tile[32][33];
  const int t = threadIdx.x;
  const int tr = t & 31, tc = t >> 5;          // 32 x 8
  const int r0 = blockIdx.x * 32, c0 = blockIdx.y * 32;
#pragma unroll
  for (int i = 0; i < 4; ++i)
    tile[tc + i * 8][tr] = src[(size_t)(r0 + tc + i * 8) * C + c0 + tr];
  __syncthreads();
#pragma unroll
  for (int i = 0; i < 4; ++i)
    dst[(size_t)(c0 + tc + i * 8) * R + r0 + tr] = f2b(tile[tr][tc + i * 8]);
}

// ---------------- bf16 MFMA GEMM: C[M,N] = A[M,K] * Bt[N,K]^T ----------------
// 128x128 tile, BK=32, 4 waves each 64x64, 16x16x32 MFMA, global_load_lds staging.
__global__ __launch_bounds__(256) void gemm_bt(
    const u16* __restrict__ A,   // [M,K] bf16
    const u16* __restrict__ Bt,  // [N,K] bf16
    u16* __restrict__ C,         // [M,N] bf16
    int M, int N, int K)
{
  __shared__ u16 As[128 * 32];   // [m][k], contiguous (global_load_lds layout)
  __shared__ u16 Bs[128 * 32];   // [n][k]

  const int t = threadIdx.x;
  const int w = t >> 6, lane = t & 63;
  const int quad = lane >> 4, l16 = lane & 15;
  const int n0 = blockIdx.x * 128, m0 = blockIdx.y * 128;
  const int wm = (w >> 1) * 64, wn = (w & 1) * 64;

  f4 acc[4][4];
#pragma unroll
  for (int mi = 0; mi < 4; ++mi)
#pragma unroll
    for (int ni = 0; ni < 4; ++ni) acc[mi][ni] = (f4){0.f, 0.f, 0.f, 0.f};

  const u16* Ap = A + (size_t)m0 * K;
  const u16* Bp = Bt + (size_t)n0 * K;
  const int srow = t >> 2, spos = (t & 3) * 8;   // chunk c=t: row c>>2, kpos (c&3)*8

  for (int k0 = 0; k0 < K; k0 += 32) {
    __syncthreads();
    load_lds16(Ap + (size_t)srow * K + k0 + spos,        &As[(size_t)t * 8]);
    load_lds16(Ap + (size_t)(srow + 64) * K + k0 + spos, &As[(size_t)(256 + t) * 8]);
    load_lds16(Bp + (size_t)srow * K + k0 + spos,        &Bs[(size_t)t * 8]);
    load_lds16(Bp + (size_t)(srow + 64) * K + k0 + spos, &Bs[(size_t)(256 + t) * 8]);
    __syncthreads();

    bf8 af[4], bfr[4];
#pragma unroll
    for (int mi = 0; mi < 4; ++mi)
      af[mi] = *(const bf8*)(&As[(wm + mi * 16 + l16) * 32 + quad * 8]);
#pragma unroll
    for (int ni = 0; ni < 4; ++ni)
      bfr[ni] = *(const bf8*)(&Bs[(wn + ni * 16 + l16) * 32 + quad * 8]);
#pragma unroll
    for (int mi = 0; mi < 4; ++mi)
#pragma unroll
      for (int ni = 0; ni < 4; ++ni)
        acc[mi][ni] = __builtin_amdgcn_mfma_f32_16x16x32_bf16(af[mi], bfr[ni], acc[mi][ni], 0, 0, 0);
  }

  u16* Cp = C + (size_t)m0 * N + n0;
#pragma unroll
  for (int mi = 0; mi < 4; ++mi)
#pragma unroll
    for (int r = 0; r < 4; ++r) {
      int m = wm + mi * 16 + quad * 4 + r;
#pragma unroll
      for (int ni = 0; ni < 4; ++ni)
        Cp[(size_t)m * N + wn + ni * 16 + l16] = f2b(acc[mi][ni][r]);
    }
}

// ---------------- transpose vupB [B,NKV,H,HD](bf16) -> vupT [B,H,HD,NKV](bf16) ----------------
__global__ __launch_bounds__(256) void transpose_v(const u16* __restrict__ vupB,
                                                   u16* __restrict__ vupT)
{
  __shared__ u16 tile[64][78];
  const int t = threadIdx.x;
  const int key0 = blockIdx.x * 64, d0 = blockIdx.y * 64;
  const int bh = blockIdx.z, b = bh >> 4, h = bh & 15;

#pragma unroll
  for (int i = 0; i < 2; ++i) {
    int c = t + 256 * i;           // 512 chunks
    int key = c >> 3, d8 = c & 7;
    bf8 v = *(const bf8*)(vupB + ((size_t)(b * N_ + key0 + key) * (H_ * HD_)) + h * HD_ + d0 + d8 * 8);
    *(bf8*)(&tile[key][d8 * 8]) = v;
  }
  __syncthreads();
#pragma unroll
  for (int i = 0; i < 2; ++i) {
    int c = t + 256 * i;
    int d = c >> 3, k8 = c & 7;
    bf8 v;
#pragma unroll
    for (int j = 0; j < 8; ++j) v[j] = (short)tile[k8 * 8 + j][d];
    *(bf8*)(vupT + ((size_t)bh * HD_ + d0 + d) * (size_t)N_ + key0 + k8 * 8) = v;
  }
}

// ---------------- flash attention: bf16 MFMA, online softmax ----------------
__global__ __launch_bounds__(256, 2) void flash_mfma(
    const u16* __restrict__ q2b,   // [B,N,H,LKV] bf16
    const u16* __restrict__ ckvb,  // [B,NKV,LKV] bf16
    const u16* __restrict__ vupT,  // [B,H,HD,NKV] bf16
    float* __restrict__ out)       // [B,N,H*HD] fp32
{
  __shared__ u16 KtL[32 * 264];
  __shared__ u16 VtL[256 * 40];
  __shared__ u16 PtL[128 * 40];

  const int t = threadIdx.x;
  const int w = t >> 6, lane = t & 63;
  const int quad = lane >> 4, l16 = lane & 15;
  const int n0 = blockIdx.x * 128;
  const int bh = blockIdx.y, b = bh >> 4, h = bh & 15;

  bf8 qf[2][8];
  {
    const u16* qbase = q2b + (size_t)(b * N_ + n0 + w * 32 + l16) * (H_ * LKV_) + h * LKV_ + quad * 8;
#pragma unroll
    for (int mi = 0; mi < 2; ++mi)
#pragma unroll
      for (int ks = 0; ks < 8; ++ks)
        qf[mi][ks] = *(const bf8*)(qbase + (size_t)(mi * 16) * (H_ * LKV_) + ks * 32);
  }

  f4 o[2][16];
#pragma unroll
  for (int mi = 0; mi < 2; ++mi)
#pragma unroll
    for (int dt = 0; dt < 16; ++dt) o[mi][dt] = (f4){0.f, 0.f, 0.f, 0.f};
  float ms[2][4], ls[2][4];
#pragma unroll
  for (int mi = 0; mi < 2; ++mi)
#pragma unroll
    for (int r = 0; r < 4; ++r) { ms[mi][r] = -1e30f; ls[mi][r] = 0.f; }

  const u16* kgb = ckvb + (size_t)b * N_ * LKV_;
  const u16* vgb = vupT + (size_t)bh * HD_ * N_;

  for (int k0 = 0; k0 < N_; k0 += 32) {
    __syncthreads();
#pragma unroll
    for (int i = 0; i < 4; ++i) {
      int c = t + 256 * i;
      int key = c >> 5, l8 = c & 31;
      bf8 v = *(const bf8*)(kgb + (size_t)(k0 + key) * LKV_ + l8 * 8);
      *(bf8*)(&KtL[key * 264 + l8 * 8]) = v;
    }
#pragma unroll
    for (int i = 0; i < 4; ++i) {
      int c = t + 256 * i;
      int d = c >> 2, k8 = c & 3;
      bf8 v = *(const bf8*)(vgb + (size_t)d * N_ + k0 + k8 * 8);
      *(bf8*)(&VtL[d * 40 + k8 * 8]) = v;
    }
    __syncthreads();

    f4 sf[2][2];
    sf[0][0] = (f4){0,0,0,0}; sf[0][1] = (f4){0,0,0,0};
    sf[1][0] = (f4){0,0,0,0}; sf[1][1] = (f4){0,0,0,0};
#pragma unroll
    for (int nt = 0; nt < 2; ++nt) {
      const u16* kr = &KtL[(nt * 16 + l16) * 264 + quad * 8];
#pragma unroll
      for (int ks = 0; ks < 8; ++ks) {
        bf8 kf = *(const bf8*)(kr + ks * 32);
        sf[0][nt] = __builtin_amdgcn_mfma_f32_16x16x32_bf16(qf[0][ks], kf, sf[0][nt], 0, 0, 0);
        sf[1][nt] = __builtin_amdgcn_mfma_f32_16x16x32_bf16(qf[1][ks], kf, sf[1][nt], 0, 0, 0);
      }
    }

#pragma unroll
    for (int mi = 0; mi < 2; ++mi) {
      float al[4];
#pragma unroll
      for (int r = 0; r < 4; ++r) {
        float a0 = sf[mi][0][r] * 0.0625f;
        float a1 = sf[mi][1][r] * 0.0625f;
        float mx = fmaxf(a0, a1);
#pragma unroll
        for (int off = 1; off < 16; off <<= 1) mx = fmaxf(mx, __shfl_xor(mx, off, 16));
        float mn = fmaxf(ms[mi][r], mx);
        float p0 = __expf(a0 - mn), p1 = __expf(a1 - mn);
        float sum = p0 + p1;
#pragma unroll
        for (int off = 1; off < 16; off <<= 1) sum += __shfl_xor(sum, off, 16);
        al[r] = __expf(ms[mi][r] - mn);
        ls[mi][r] = ls[mi][r] * al[r] + sum;
        ms[mi][r] = mn;
        int q = w * 32 + mi * 16 + quad * 4 + r;
        PtL[q * 40 + l16]      = f2b(p0);
        PtL[q * 40 + 16 + l16] = f2b(p1);
      }
#pragma unroll
      for (int dt = 0; dt < 16; ++dt) {
        o[mi][dt][0] *= al[0]; o[mi][dt][1] *= al[1];
        o[mi][dt][2] *= al[2]; o[mi][dt][3] *= al[3];
      }
    }
    __syncthreads();

    bf8 pf0 = *(const bf8*)(&PtL[(w * 32 + l16) * 40 + quad * 8]);
    bf8 pf1 = *(const bf8*)(&PtL[(w * 32 + 16 + l16) * 40 + quad * 8]);
#pragma unroll
    for (int dt = 0; dt < 16; ++dt) {
      bf8 vf = *(const bf8*)(&VtL[(dt * 16 + l16) * 40 + quad * 8]);
      o[0][dt] = __builtin_amdgcn_mfma_f32_16x16x32_bf16(pf0, vf, o[0][dt], 0, 0, 0);
      o[1][dt] = __builtin_amdgcn_mfma_f32_16x16x32_bf16(pf1, vf, o[1][dt], 0, 0, 0);
    }
  }

#pragma unroll
  for (int mi = 0; mi < 2; ++mi)
#pragma unroll
    for (int r = 0; r < 4; ++r) {
      float iv = 1.f / ls[mi][r];
      float* dst = out + (size_t)(b * N_ + n0 + w * 32 + mi * 16 + quad * 4 + r) * (H_ * HD_)
                   + h * HD_ + l16;
#pragma unroll
      for (int dt = 0; dt < 16; ++dt) dst[dt * 16] = o[mi][dt][r] * iv;
    }
}

extern "C" void kernel_launch(void* const* d_in, const int* in_sizes, int n_in,
                              void* d_out, int out_size, void* d_ws, size_t ws_size,
                              hipStream_t stream) {
  const float* Q     = (const float*)d_in[0];  // [2,2048,4096]
  const float* Kin   = (const float*)d_in[1];  // [2,2048,4096]
  const float* Wq_d  = (const float*)d_in[2];  // [4096,512]
  const float* W_qk  = (const float*)d_in[3];  // [512,4096]
  const float* Wkv_d = (const float*)d_in[4];  // [4096,256]
  const float* Wv_u  = (const float*)d_in[5];  // [256,4096]
  float* out = (float*)d_out;

  char* ws = (char*)d_ws;
  // aliasing: qbf reused as vupT (qbf dead after C_q GEMM);
  //           kbf reused as vupB (kbf dead after C_kv GEMM). total 114 MB.
  u16* qbf   = (u16*)(ws);                    // 32 MB bf16 [4096,4096]
  u16* vupT  = qbf;                           //        bf16 [B,H,256,2048]
  u16* kbf   = (u16*)(ws + 33554432);         // 32 MB bf16 [4096,4096]
  u16* vupB  = kbf;                           //        bf16 [4096,4096]
  u16* q2b   = (u16*)(ws + 67108864);         // 32 MB bf16 [4096,4096]
  u16* cqb   = (u16*)(ws + 100663296);        //  4 MB bf16 [4096,512]
  u16* ckvb  = (u16*)(ws + 104857600);        //  2 MB bf16 [4096,256]
  u16* wqdT  = (u16*)(ws + 106954752);        //  4 MB bf16 [512,4096]
  u16* wqkT  = (u16*)(ws + 111149056);        //  4 MB bf16 [4096,512]
  u16* wkvdT = (u16*)(ws + 115343360);        //  2 MB bf16 [256,4096]
  u16* wvuT  = (u16*)(ws + 117440512);        //  2 MB bf16 [4096,256]

  // input converts
  cvt_bf16<<<dim3(16384), 256, 0, stream>>>(Q,   qbf, 4194304);
  cvt_bf16<<<dim3(16384), 256, 0, stream>>>(Kin, kbf, 4194304);
  // weight convert+transpose: [R,C] fp32 -> [C,R] bf16
  cvt_transpose<<<dim3(128, 16), 256, 0, stream>>>(Wq_d,  wqdT,  4096, 512);
  cvt_transpose<<<dim3(16, 128), 256, 0, stream>>>(W_qk,  wqkT,  512, 4096);
  cvt_transpose<<<dim3(128, 8),  256, 0, stream>>>(Wkv_d, wkvdT, 4096, 256);
  cvt_transpose<<<dim3(8, 128),  256, 0, stream>>>(Wv_u,  wvuT,  256, 4096);

  // C_q = Q @ Wq_d           [4096,512]  K=4096
  gemm_bt<<<dim3(4, 32), 256, 0, stream>>>(qbf, wqdT, cqb, 4096, 512, 4096);
  // C_kv = K @ Wkv_d         [4096,256]  K=4096
  gemm_bt<<<dim3(2, 32), 256, 0, stream>>>(kbf, wkvdT, ckvb, 4096, 256, 4096);
  // Q2 = C_q @ W_qk          [4096,4096] K=512
  gemm_bt<<<dim3(32, 32), 256, 0, stream>>>(cqb, wqkT, q2b, 4096, 4096, 512);
  // V_up = C_kv @ Wv_u       [4096,4096] K=256   (overwrites kbf region)
  gemm_bt<<<dim3(32, 32), 256, 0, stream>>>(ckvb, wvuT, vupB, 4096, 4096, 256);
  // V transpose (overwrites qbf region)
  transpose_v<<<dim3(32, 4, 32), 256, 0, stream>>>(vupB, vupT);
  // flash attention
  flash_mfma<<<dim3(16, 32), 256, 0, stream>>>(q2b, ckvb, vupT, out);
}